// Round 3
// baseline (29.725 us; speedup 1.0000x reference)
//
#include <hip/hip_runtime.h>

// Problem constants (fixed by the reference)
#define N_ROWS 4096
#define D_DIM  1024
#define NCLS   10

// loss = ( ||s||_F^2 + ||t||_F^2 - 2 * sum_c S_c . T_c / n_c ) / N
// where S_c, T_c are per-class column sums. Two streaming kernels.

#define CHUNK     32
#define NCHUNK    (N_ROWS / CHUNK)          // 128
#define SLICE_W   512
#define NSLICE    (D_DIM / SLICE_W)         // 2
#define K1_BLOCKS (2 * NSLICE * NCHUNK)     // 512 (both matrices)
#define K2_BLOCKS 40
#define CS        (NCLS * SLICE_W)          // 5120 floats: chunk stride in partials

// ws float-offsets (deterministic path; nothing needs pre-zeroing except the
// k2 ticket counter, which k1 resets every launch)
#define OFF_CTR   0                          // 1 int
#define OFF_ACC2  16                         // 512 floats: per-k1-block sum-of-squares
#define OFF_DOTP  (OFF_ACC2 + K1_BLOCKS)     // 528: 40 floats
#define OFF_PART  544                        // 16B-aligned
#define PART_FLOATS (NSLICE * NCHUNK * NCLS * SLICE_W)   // 1,310,720 per matrix
#define NEED_FLOATS (OFF_PART + 2 * PART_FLOATS)         // ~10.5 MB

// fallback (atomic) layout
#define OFF_FBS   544                        // 2*10*1024 floats class sums
#define FB_FLOATS (OFF_FBS + 2 * NCLS * D_DIM)

// ---------------------------------------------------------------------------
// k1: one streaming pass over both matrices. Block = (mat, slice, 32-row
// chunk). Per-thread: 2 cols x 32 rows, float2 loads in 16-deep batches.
// Class accumulation via wave-uniform scalar switch (2 VALU adds/elem).
__global__ __launch_bounds__(256) void k_pass1(const float* __restrict__ fm_s,
                                               const float* __restrict__ fm_t,
                                               const int* __restrict__ tgt,
                                               float* __restrict__ ws) {
    const int bid = blockIdx.x, tid = threadIdx.x;
    const int mat   = bid >> 8;          // 0 = s, 1 = t
    const int rem   = bid & 255;
    const int slice = rem >> 7;          // 0..1
    const int chunk = rem & 127;         // 0..127

    if (bid == 0 && tid == 0) ((int*)ws)[OFF_CTR] = 0;   // reset k2 ticket

    __shared__ int tl[CHUNK];
    if (tid < CHUNK) tl[tid] = tgt[chunk * CHUNK + tid];
    __syncthreads();

    const float* src  = mat ? fm_t : fm_s;
    const float* base = src + (size_t)chunk * CHUNK * D_DIM + slice * SLICE_W + tid * 2;

    float2 a[NCLS];
#pragma unroll
    for (int k = 0; k < NCLS; ++k) a[k] = make_float2(0.f, 0.f);
    float acc2 = 0.f;

#pragma unroll
    for (int r0 = 0; r0 < CHUNK; r0 += 16) {
        float2 v[16];
#pragma unroll
        for (int j = 0; j < 16; ++j)
            v[j] = *(const float2*)(base + (size_t)(r0 + j) * D_DIM);
#pragma unroll
        for (int j = 0; j < 16; ++j) {
            const float x = v[j].x, y = v[j].y;
            acc2 += x * x + y * y;
            const int c = __builtin_amdgcn_readfirstlane(tl[r0 + j]);  // wave-uniform
            switch (c) {
                case 0: a[0].x += x; a[0].y += y; break;
                case 1: a[1].x += x; a[1].y += y; break;
                case 2: a[2].x += x; a[2].y += y; break;
                case 3: a[3].x += x; a[3].y += y; break;
                case 4: a[4].x += x; a[4].y += y; break;
                case 5: a[5].x += x; a[5].y += y; break;
                case 6: a[6].x += x; a[6].y += y; break;
                case 7: a[7].x += x; a[7].y += y; break;
                case 8: a[8].x += x; a[8].y += y; break;
                default: a[9].x += x; a[9].y += y; break;
            }
        }
    }

    // partials layout: [mat][slice][chunk][cls][col-in-slice]
    float* part = ws + OFF_PART + (size_t)mat * PART_FLOATS
                + (size_t)(slice * NCHUNK + chunk) * CS + tid * 2;
#pragma unroll
    for (int k = 0; k < NCLS; ++k)
        *(float2*)(part + (size_t)k * SLICE_W) = a[k];

    __shared__ float red[256];
    red[tid] = acc2;
    __syncthreads();
    for (int s = 128; s > 0; s >>= 1) {
        if (tid < s) red[tid] += red[tid + s];
        __syncthreads();
    }
    if (tid == 0) ws[OFF_ACC2 + bid] = red[0];
}

// ---------------------------------------------------------------------------
// k2: reduce partials -> per-class dot products -> final loss (last block).
// Block b: cls = b/4, quarter of the 1024 cols (64 float4 lanes). 4 waves:
// g = (mat, chunk-half). float4 loads, 16-deep.
__global__ __launch_bounds__(256) void k_pass2(const int* __restrict__ tgt,
                                               float* __restrict__ ws,
                                               float* __restrict__ out) {
    const int b = blockIdx.x, tid = threadIdx.x;
    const int cls  = b >> 2;
    const int colq = b & 3;
    const int g    = tid >> 6;            // wave id: 0..3
    const int ct   = tid & 63;
    const int mat  = g >> 1;              // 0: s, 1: t
    const int half = g & 1;               // chunk half
    const int slice = colq >> 1;          // quarter lives in one slice
    const int c512  = (colq & 1) * 256 + ct * 4;

    const float* p = ws + OFF_PART + (size_t)mat * PART_FLOATS
                   + (size_t)slice * ((size_t)NCHUNK * CS)
                   + (size_t)(half * 64) * CS
                   + (size_t)cls * SLICE_W + c512;

    float4 s0 = {0,0,0,0}, s1 = {0,0,0,0}, s2 = {0,0,0,0}, s3 = {0,0,0,0};
#pragma unroll
    for (int c0 = 0; c0 < 64; c0 += 16) {
        float4 v[16];
#pragma unroll
        for (int j = 0; j < 16; ++j)
            v[j] = *(const float4*)(p + (size_t)(c0 + j) * CS);
#pragma unroll
        for (int j = 0; j < 16; ++j) {
            float4& acc = ((j & 3) == 0) ? s0 : ((j & 3) == 1) ? s1 : ((j & 3) == 2) ? s2 : s3;
            acc.x += v[j].x; acc.y += v[j].y; acc.z += v[j].z; acc.w += v[j].w;
        }
    }
    float4 sum;
    sum.x = (s0.x + s1.x) + (s2.x + s3.x);
    sum.y = (s0.y + s1.y) + (s2.y + s3.y);
    sum.z = (s0.z + s1.z) + (s2.z + s3.z);
    sum.w = (s0.w + s1.w) + (s2.w + s3.w);

    __shared__ float4 red4[4][64];
    red4[g][ct] = sum;
    __syncthreads();

    __shared__ float prodRed[64];
    if (tid < 64) {
        float4 A, B;
        A.x = red4[0][tid].x + red4[1][tid].x;
        A.y = red4[0][tid].y + red4[1][tid].y;
        A.z = red4[0][tid].z + red4[1][tid].z;
        A.w = red4[0][tid].w + red4[1][tid].w;
        B.x = red4[2][tid].x + red4[3][tid].x;
        B.y = red4[2][tid].y + red4[3][tid].y;
        B.z = red4[2][tid].z + red4[3][tid].z;
        B.w = red4[2][tid].w + red4[3][tid].w;
        prodRed[tid] = A.x * B.x + A.y * B.y + A.z * B.z + A.w * B.w;
    }
    __syncthreads();
    for (int s = 32; s > 0; s >>= 1) {
        if (tid < s) prodRed[tid] += prodRed[tid + s];
        __syncthreads();
    }

    // last-block ticket (device-scope fences: G16 XCD non-coherence)
    __shared__ int isLast;
    if (tid == 0) {
        ws[OFF_DOTP + b] = prodRed[0];
        __threadfence();
        int old = atomicAdd((int*)ws + OFF_CTR, 1);
        isLast = (old == K2_BLOCKS - 1) ? 1 : 0;
    }
    __syncthreads();
    if (!isLast) return;
    __threadfence();

    __shared__ int hist[NCLS];
    if (tid < NCLS) hist[tid] = 0;
    __syncthreads();
    for (int i = tid; i < N_ROWS; i += 256) atomicAdd(&hist[tgt[i]], 1);
    __syncthreads();

    double v = (double)ws[OFF_ACC2 + tid] + (double)ws[OFF_ACC2 + tid + 256];
    if (tid < K2_BLOCKS) {
        int n = hist[tid >> 2];
        if (n > 0) v -= 2.0 * (double)ws[OFF_DOTP + tid] / (double)n;
    }
    __shared__ double dred[256];
    dred[tid] = v;
    __syncthreads();
    for (int s = 128; s > 0; s >>= 1) {
        if (tid < s) dred[tid] += dred[tid + s];
        __syncthreads();
    }
    if (tid == 0) out[0] = (float)(dred[0] / (double)N_ROWS);
}

// ------------------------- atomic fallback (tiny ws; never expected) --------
__global__ void k_fb_zero(float* __restrict__ ws) {
    int i = blockIdx.x * 256 + threadIdx.x;
    if (i < 2 * NCLS * D_DIM) ws[OFF_FBS + i] = 0.f;
}

__global__ __launch_bounds__(256) void k_fb_acc(const float* __restrict__ fm_s,
                                                const float* __restrict__ fm_t,
                                                const int* __restrict__ tgt,
                                                float* __restrict__ ws) {
    const int bid = blockIdx.x, tid = threadIdx.x;
    const int mat   = bid >> 8;
    const int rem   = bid & 255;
    const int slice = rem >> 7;
    const int chunk = rem & 127;

    __shared__ int tl[CHUNK];
    if (tid < CHUNK) tl[tid] = tgt[chunk * CHUNK + tid];
    __syncthreads();

    const float* src  = mat ? fm_t : fm_s;
    const float* base = src + (size_t)chunk * CHUNK * D_DIM + slice * SLICE_W + tid * 2;

    float2 a[NCLS];
#pragma unroll
    for (int k = 0; k < NCLS; ++k) a[k] = make_float2(0.f, 0.f);
    float acc2 = 0.f;

    for (int r = 0; r < CHUNK; ++r) {
        float2 v = *(const float2*)(base + (size_t)r * D_DIM);
        acc2 += v.x * v.x + v.y * v.y;
        const int c = __builtin_amdgcn_readfirstlane(tl[r]);
        switch (c) {
            case 0: a[0].x += v.x; a[0].y += v.y; break;
            case 1: a[1].x += v.x; a[1].y += v.y; break;
            case 2: a[2].x += v.x; a[2].y += v.y; break;
            case 3: a[3].x += v.x; a[3].y += v.y; break;
            case 4: a[4].x += v.x; a[4].y += v.y; break;
            case 5: a[5].x += v.x; a[5].y += v.y; break;
            case 6: a[6].x += v.x; a[6].y += v.y; break;
            case 7: a[7].x += v.x; a[7].y += v.y; break;
            case 8: a[8].x += v.x; a[8].y += v.y; break;
            default: a[9].x += v.x; a[9].y += v.y; break;
        }
    }

    int col = slice * SLICE_W + tid * 2;
    float* dst = ws + OFF_FBS + (size_t)mat * NCLS * D_DIM + col;
#pragma unroll
    for (int k = 0; k < NCLS; ++k) {
        atomicAdd(dst + (size_t)k * D_DIM,     a[k].x);
        atomicAdd(dst + (size_t)k * D_DIM + 1, a[k].y);
    }

    __shared__ float red[256];
    red[tid] = acc2;
    __syncthreads();
    for (int s = 128; s > 0; s >>= 1) {
        if (tid < s) red[tid] += red[tid + s];
        __syncthreads();
    }
    if (tid == 0) ws[OFF_ACC2 + bid] = red[0];
}

__global__ __launch_bounds__(256) void k_fb_fin(const int* __restrict__ tgt,
                                                float* __restrict__ ws,
                                                float* __restrict__ out) {
    const int tid = threadIdx.x;
    __shared__ int hist[NCLS];
    if (tid < NCLS) hist[tid] = 0;
    __syncthreads();
    for (int i = tid; i < N_ROWS; i += 256) atomicAdd(&hist[tgt[i]], 1);
    __syncthreads();

    double v = (double)ws[OFF_ACC2 + tid] + (double)ws[OFF_ACC2 + tid + 256];
    for (int i = tid; i < NCLS * D_DIM; i += 256) {
        int n = hist[i >> 10];
        if (n > 0) {
            double sS = ws[OFF_FBS + i];
            double sT = ws[OFF_FBS + NCLS * D_DIM + i];
            v -= 2.0 * sS * sT / (double)n;
        }
    }
    __shared__ double dred[256];
    dred[tid] = v;
    __syncthreads();
    for (int s = 128; s > 0; s >>= 1) {
        if (tid < s) dred[tid] += dred[tid + s];
        __syncthreads();
    }
    if (tid == 0) out[0] = (float)(dred[0] / (double)N_ROWS);
}

// ---------------------------------------------------------------------------
extern "C" void kernel_launch(void* const* d_in, const int* in_sizes, int n_in,
                              void* d_out, int out_size, void* d_ws, size_t ws_size,
                              hipStream_t stream) {
    const float* fm_s = (const float*)d_in[0];
    const float* fm_t = (const float*)d_in[1];
    const int*   tgt  = (const int*)d_in[2];
    // d_in[3] (fusion_true) unused: reference takes the fusion_true==0 branch.

    float* ws   = (float*)d_ws;
    float* outp = (float*)d_out;

    if (ws_size >= (size_t)NEED_FLOATS * sizeof(float)) {
        k_pass1<<<K1_BLOCKS, 256, 0, stream>>>(fm_s, fm_t, tgt, ws);
        k_pass2<<<K2_BLOCKS, 256, 0, stream>>>(tgt, ws, outp);
    } else {
        k_fb_zero<<<(2 * NCLS * D_DIM + 255) / 256, 256, 0, stream>>>(ws);
        k_fb_acc<<<K1_BLOCKS, 256, 0, stream>>>(fm_s, fm_t, tgt, ws);
        k_fb_fin<<<1, 256, 0, stream>>>(tgt, ws, outp);
    }
}